// Round 8
// baseline (217.825 us; speedup 1.0000x reference)
//
#include <hip/hip_runtime.h>
#include <hip/hip_bf16.h>

#define NN 50000
#define EE 800000
#define DD 128
#define CB 196      // coarse buckets of 256 nodes (196*256 = 50176)
#define EBLK 4096
#define NEB 196     // ceil(EE/EBLK) = 196 (195*4096=798720, last block 1280)

typedef __attribute__((ext_vector_type(8))) short bf16x8;
typedef __attribute__((ext_vector_type(4))) float f32x4;

static __device__ __forceinline__ unsigned short f2bf(float f) {
  union { float f; unsigned u; } v; v.f = f;
  unsigned r = v.u + 0x7FFFu + ((v.u >> 16) & 1u);
  return (unsigned short)(r >> 16);
}
static __device__ __forceinline__ float bf2f(unsigned short h) {
  union { unsigned u; float f; } v; v.u = ((unsigned)h) << 16;
  return v.f;
}

// blocks [0,196): coarse LDS histogram of dst>>8 AND global deg atomics.
// blocks [196,228): Wt[n][k] bf16 combined (k<128: W_gcn, k>=128: W_lin).
// blocks [228,1791): x -> bf16 xb (unscaled).
__global__ __launch_bounds__(256) void k_p0(
    const int* __restrict__ dst, int* __restrict__ coarseCnt,
    int* __restrict__ deg,
    const float* __restrict__ Wg, const float* __restrict__ Wl,
    unsigned short* __restrict__ Wt, const float4* __restrict__ x4,
    ushort4* __restrict__ xb4) {
  int b = blockIdx.x, t = threadIdx.x;
  if (b < NEB) {
    __shared__ int cnt[CB];
    for (int i = t; i < CB; i += 256) cnt[i] = 0;
    __syncthreads();
    int e0 = b * EBLK;
    for (int i = t; i < EBLK; i += 256) {
      int e = e0 + i;
      if (e < EE) {
        int d = dst[e];
        atomicAdd(&cnt[d >> 8], 1);
        atomicAdd(&deg[d], 1);
      }
    }
    __syncthreads();
    for (int i = t; i < CB; i += 256)
      if (cnt[i]) atomicAdd(&coarseCnt[i], cnt[i]);
  } else if (b < NEB + 32) {
    for (int i = (b - NEB) * 256 + t; i < DD * 256; i += 32 * 256) {
      int n = i >> 8, k = i & 255;
      float v = (k < 128) ? Wg[k * DD + n] : Wl[(k - 128) * DD + n];
      Wt[i] = f2bf(v);
    }
  } else {
    int base = (b - NEB - 32) * 1024 + t;
#pragma unroll
    for (int k = 0; k < 4; k++) {
      int i = base + k * 256;
      if (i < NN * 32) {
        float4 v = x4[i];
        ushort4 o;
        o.x = f2bf(v.x); o.y = f2bf(v.y); o.z = f2bf(v.z); o.w = f2bf(v.w);
        xb4[i] = o;
      }
    }
  }
}

// Bin edges into coarse-bucket runs. Self-computes bucket bases from
// coarseCnt (LDS scan) -- no separate pscan dispatch.
// Record: src(16b) | dlocal(8b)<<16 | coarse(8b)<<24.
__global__ __launch_bounds__(512) void k_p1a(const int* __restrict__ src,
                                             const int* __restrict__ dst,
                                             const int* __restrict__ coarseCnt,
                                             int* __restrict__ cursor0,
                                             unsigned int* __restrict__ pairs) {
  __shared__ unsigned int stage[EBLK];   // 16 KB
  __shared__ int sc[256];
  __shared__ int cnt[CB], rb[CB], cur[CB];
  int t = threadIdx.x;
  int e0 = blockIdx.x * EBLK;
  int own = 0;
  if (t < CB) { cnt[t] = 0; cur[t] = 0; }
  if (t < 256) { own = (t < CB) ? coarseCnt[t] : 0; sc[t] = own; }
  __syncthreads();
  for (int i = t; i < EBLK; i += 512) {
    int e = e0 + i;
    unsigned int p = 0xFFFFFFFFu;
    if (e < EE) {
      int d = dst[e], s = src[e];
      int cb = d >> 8;
      p = (unsigned int)s | ((unsigned int)(d & 255) << 16) | ((unsigned int)cb << 24);
      atomicAdd(&cnt[cb], 1);
    }
    stage[i] = p;
  }
  // inclusive scan of sc[0..255] (bases from global coarseCnt)
  for (int off = 1; off < 256; off <<= 1) {
    __syncthreads();
    int tmp = (t < 256 && t >= off) ? sc[t - off] : 0;
    __syncthreads();
    if (t < 256 && t >= off) sc[t] += tmp;
  }
  __syncthreads();   // also guarantees count loop + cnt[] complete
  if (t < CB) {
    int excl = sc[t] - own;
    rb[t] = excl + (cnt[t] ? atomicAdd(&cursor0[t], cnt[t]) : 0);
  }
  __syncthreads();
  for (int i = t; i < EBLK; i += 512) {
    unsigned int p = stage[i];
    if (p != 0xFFFFFFFFu) {
      int cb = p >> 24;
      int ofs = atomicAdd(&cur[cb], 1);
      pairs[rb[cb] + ofs] = p;
    }
  }
}

// One block per coarse bucket: uses global deg (no pairs histogram pass).
// Computes coarseStart by reduction, scans deg -> rowStart/dinv, scatters
// pairs -> u16 srcList, converts xs = dinv*xb rows.
__global__ __launch_bounds__(512) void k_p1b(
    const unsigned int* __restrict__ pairs, const int* __restrict__ coarseCnt,
    const int* __restrict__ deg, const unsigned short* __restrict__ xb,
    float* __restrict__ dinv, int* __restrict__ rowStart,
    unsigned short* __restrict__ srcU16, unsigned short* __restrict__ xs) {
  __shared__ int sc[256], lcur[256];
  __shared__ float ldinvs[256];
  __shared__ int wsum[8];
  int b = blockIdx.x, t = threadIdx.x;
  int n0 = b << 8;
  int nloc = NN - n0; if (nloc > 256) nloc = 256;
  // coarseStart = sum(coarseCnt[0..b-1]) via strided partial + wave reduce
  int partial = 0;
  for (int i = t; i < b; i += 512) partial += coarseCnt[i];
#pragma unroll
  for (int off = 32; off > 0; off >>= 1) partial += __shfl_xor(partial, off);
  if ((t & 63) == 0) wsum[t >> 6] = partial;
  // deg load + scan
  int dg = 0;
  if (t < 256) {
    dg = (t < nloc) ? deg[n0 + t] : 0;
    sc[t] = dg;
  }
  for (int off = 1; off < 256; off <<= 1) {
    __syncthreads();
    int tmp = (t < 256 && t >= off) ? sc[t - off] : 0;
    __syncthreads();
    if (t < 256 && t >= off) sc[t] += tmp;
  }
  __syncthreads();
  int start = wsum[0] + wsum[1] + wsum[2] + wsum[3] +
              wsum[4] + wsum[5] + wsum[6] + wsum[7];
  int cnt = sc[255];
  if (t < 256) {
    int rs = start + sc[t] - dg;
    lcur[t] = rs;
    float di = rsqrtf((float)(dg + 1));
    ldinvs[t] = di;
    if (t < nloc) { rowStart[n0 + t] = rs; dinv[n0 + t] = di; }
  }
  __syncthreads();
  for (int i = t; i < cnt; i += 512) {
    unsigned int pr = pairs[start + i];
    int pos = atomicAdd(&lcur[(pr >> 16) & 255], 1);
    srcU16[pos] = (unsigned short)(pr & 0xFFFFu);
  }
  // xs rows for local nodes (pre-scaled by dinv)
  for (int i = t; i < nloc * 16; i += 512) {
    int rr = i >> 4, q = i & 15;
    bf16x8 v = *(const bf16x8*)(xb + (size_t)(n0 + rr) * DD + q * 8);
    float di = ldinvs[rr];
    bf16x8 o;
#pragma unroll
    for (int k = 0; k < 8; k++) o[k] = (short)f2bf(bf2f((unsigned short)v[k]) * di);
    *(bf16x8*)(xs + (size_t)(n0 + rr) * DD + q * 8) = o;
  }
}

// Pure gather: one 16-lane group per node, 16 nodes/block -> 3125 blocks.
// 8 row-loads in flight per group. agg = bf16(dinv*(xs[n] + sum xs[src])).
__global__ __launch_bounds__(256) void k_agg2(
    const unsigned short* __restrict__ xs, const int* __restrict__ rowStart,
    const int* __restrict__ deg, const unsigned short* __restrict__ srcU16,
    const float* __restrict__ dinv, unsigned short* __restrict__ agg) {
  int t = threadIdx.x;
  int g = t >> 4, r = t & 15;
  int node = blockIdx.x * 16 + g;      // exact: 3125*16 = 50000
  int lane = t & 63;
  int srcLaneBase = lane & 48;
  float acc[8];
  {
    bf16x8 vs = *(const bf16x8*)(xs + (size_t)node * DD + r * 8);
#pragma unroll
    for (int k = 0; k < 8; k++) acc[k] = bf2f((unsigned short)vs[k]);
  }
  int js = rowStart[node], cnt = deg[node];
  for (int base = 0; base < cnt; base += 16) {
    int idx = (base + r < cnt) ? (int)srcU16[js + base + r] : 0;
    int m = cnt - base; if (m > 16) m = 16;
    int j = 0;
    for (; j + 8 <= m; j += 8) {  // 8 independent row-loads in flight
      int s0 = __shfl(idx, srcLaneBase + j);
      int s1 = __shfl(idx, srcLaneBase + j + 1);
      int s2 = __shfl(idx, srcLaneBase + j + 2);
      int s3 = __shfl(idx, srcLaneBase + j + 3);
      int s4 = __shfl(idx, srcLaneBase + j + 4);
      int s5 = __shfl(idx, srcLaneBase + j + 5);
      int s6 = __shfl(idx, srcLaneBase + j + 6);
      int s7 = __shfl(idx, srcLaneBase + j + 7);
      bf16x8 v0 = *(const bf16x8*)(xs + (size_t)s0 * DD + r * 8);
      bf16x8 v1 = *(const bf16x8*)(xs + (size_t)s1 * DD + r * 8);
      bf16x8 v2 = *(const bf16x8*)(xs + (size_t)s2 * DD + r * 8);
      bf16x8 v3 = *(const bf16x8*)(xs + (size_t)s3 * DD + r * 8);
      bf16x8 v4 = *(const bf16x8*)(xs + (size_t)s4 * DD + r * 8);
      bf16x8 v5 = *(const bf16x8*)(xs + (size_t)s5 * DD + r * 8);
      bf16x8 v6 = *(const bf16x8*)(xs + (size_t)s6 * DD + r * 8);
      bf16x8 v7 = *(const bf16x8*)(xs + (size_t)s7 * DD + r * 8);
#pragma unroll
      for (int k = 0; k < 8; k++) acc[k] += bf2f((unsigned short)v0[k]);
#pragma unroll
      for (int k = 0; k < 8; k++) acc[k] += bf2f((unsigned short)v1[k]);
#pragma unroll
      for (int k = 0; k < 8; k++) acc[k] += bf2f((unsigned short)v2[k]);
#pragma unroll
      for (int k = 0; k < 8; k++) acc[k] += bf2f((unsigned short)v3[k]);
#pragma unroll
      for (int k = 0; k < 8; k++) acc[k] += bf2f((unsigned short)v4[k]);
#pragma unroll
      for (int k = 0; k < 8; k++) acc[k] += bf2f((unsigned short)v5[k]);
#pragma unroll
      for (int k = 0; k < 8; k++) acc[k] += bf2f((unsigned short)v6[k]);
#pragma unroll
      for (int k = 0; k < 8; k++) acc[k] += bf2f((unsigned short)v7[k]);
    }
    for (; j < m; j++) {
      int s = __shfl(idx, srcLaneBase + j);
      bf16x8 v = *(const bf16x8*)(xs + (size_t)s * DD + r * 8);
#pragma unroll
      for (int k = 0; k < 8; k++) acc[k] += bf2f((unsigned short)v[k]);
    }
  }
  float d = dinv[node];
  bf16x8 o;
#pragma unroll
  for (int k = 0; k < 8; k++) o[k] = (short)f2bf(acc[k] * d);
  *(bf16x8*)(agg + (size_t)node * DD + r * 8) = o;
}

// MFMA matmul + bias + LayerNorm. A = [agg | xb] (bf16, K=256), B^T = Wt.
__global__ __launch_bounds__(256) void k_mm_ln(
    const unsigned short* __restrict__ agg, const unsigned short* __restrict__ xb,
    const unsigned short* __restrict__ Wt, const float* __restrict__ bgcn,
    const float* __restrict__ lnw, const float* __restrict__ lnb,
    float* __restrict__ out) {
  int t = threadIdx.x;
  int w = t >> 6, lane = t & 63;
  int quad = lane >> 4, r = lane & 15;
  int m0 = (blockIdx.x * 4 + w) * 16;
  f32x4 zero = {0.f, 0.f, 0.f, 0.f};
  f32x4 acc[8];
#pragma unroll
  for (int i = 0; i < 8; i++) acc[i] = zero;
  int rowA = m0 + r;
  if (rowA > NN - 1) rowA = NN - 1;  // clamp; stores guarded
#pragma unroll
  for (int ks = 0; ks < 8; ks++) {
    bf16x8 a;
    if (ks < 4) a = *(const bf16x8*)(agg + (size_t)rowA * DD + ks * 32 + quad * 8);
    else        a = *(const bf16x8*)(xb + (size_t)rowA * DD + (ks - 4) * 32 + quad * 8);
#pragma unroll
    for (int nt = 0; nt < 8; nt++) {
      bf16x8 b = *(const bf16x8*)(Wt + (size_t)(nt * 16 + r) * 256 + ks * 32 + quad * 8);
      acc[nt] = __builtin_amdgcn_mfma_f32_16x16x32_bf16(a, b, acc[nt], 0, 0, 0);
    }
  }
  float bg[8], lw[8], lb[8];
#pragma unroll
  for (int nt = 0; nt < 8; nt++) {
    int col = nt * 16 + r;
    bg[nt] = bgcn[col] + 1e-6f;
    lw[nt] = lnw[col];
    lb[nt] = lnb[col];
  }
#pragma unroll
  for (int reg = 0; reg < 4; reg++) {
    float y[8];
    float s1 = 0.f, s2 = 0.f;
#pragma unroll
    for (int nt = 0; nt < 8; nt++) {
      y[nt] = acc[nt][reg] + bg[nt];
      s1 += y[nt];
      s2 += y[nt] * y[nt];
    }
#pragma unroll
    for (int off = 1; off < 16; off <<= 1) {
      s1 += __shfl_xor(s1, off);
      s2 += __shfl_xor(s2, off);
    }
    float mu = s1 * (1.0f / 128.0f);
    float var = s2 * (1.0f / 128.0f) - mu * mu;
    float inv = rsqrtf(var + 1e-5f);
    int row = m0 + quad * 4 + reg;
    if (row < NN) {
#pragma unroll
      for (int nt = 0; nt < 8; nt++) {
        out[(size_t)row * DD + nt * 16 + r] = (y[nt] - mu) * inv * lw[nt] + lb[nt];
      }
    }
  }
}

extern "C" void kernel_launch(void* const* d_in, const int* in_sizes, int n_in,
                              void* d_out, int out_size, void* d_ws, size_t ws_size,
                              hipStream_t stream) {
  const int* adj = (const int*)d_in[0];
  const float* x = (const float*)d_in[1];
  const float* Wg = (const float*)d_in[2];
  const float* bg = (const float*)d_in[3];
  const float* Wl = (const float*)d_in[4];
  const float* lw = (const float*)d_in[5];
  const float* lb = (const float*)d_in[6];
  const int* srcp = adj;
  const int* dstp = adj + EE;
  float* out = (float*)d_out;

  char* ws = (char*)d_ws;
  size_t off = 0;
  auto alloc = [&](size_t bytes) -> void* {
    void* p = ws + off;
    off += (bytes + 255) & ~(size_t)255;
    return p;
  };
  // one contiguous zero region: coarseCnt | cursor0 | deg
  int* zb = (int*)alloc((size_t)(256 + 256 + NN) * 4);
  int* coarseCnt = zb;
  int* cursor0 = zb + 256;
  int* deg = zb + 512;
  unsigned int* pairs = (unsigned int*)alloc((size_t)EE * 4);
  unsigned short* srcU16 = (unsigned short*)alloc((size_t)EE * 2);
  float* dinv = (float*)alloc((size_t)NN * 4);
  int* rowStart = (int*)alloc((size_t)NN * 4);
  unsigned short* xb = (unsigned short*)alloc((size_t)NN * DD * 2);
  unsigned short* xs = (unsigned short*)alloc((size_t)NN * DD * 2);
  unsigned short* agg = (unsigned short*)alloc((size_t)NN * DD * 2);
  unsigned short* Wt = (unsigned short*)alloc((size_t)DD * 256 * 2);
  (void)ws_size; (void)in_sizes; (void)n_in; (void)out_size;

  hipMemsetAsync(zb, 0, (size_t)(512 + NN) * 4, stream);
  k_p0<<<NEB + 32 + 1563, 256, 0, stream>>>(dstp, coarseCnt, deg, Wg, Wl, Wt,
                                            (const float4*)x, (ushort4*)xb);
  k_p1a<<<NEB, 512, 0, stream>>>(srcp, dstp, coarseCnt, cursor0, pairs);
  k_p1b<<<CB, 512, 0, stream>>>(pairs, coarseCnt, deg, xb, dinv, rowStart,
                                srcU16, xs);
  k_agg2<<<3125, 256, 0, stream>>>(xs, rowStart, deg, srcU16, dinv, agg);
  k_mm_ln<<<782, 256, 0, stream>>>(agg, xb, Wt, bg, lw, lb, out);
}

// Round 9
// 190.059 us; speedup vs baseline: 1.1461x; 1.1461x over previous
//
#include <hip/hip_runtime.h>
#include <hip/hip_bf16.h>

#define NN 50000
#define EE 800000
#define DD 128
#define CB 196      // coarse buckets of 256 nodes (196*256 = 50176)
#define NFB 1563    // fine buckets of 32 nodes (mega grid)
#define EBLK 4096
#define NEB 196     // ceil(EE/EBLK)

typedef __attribute__((ext_vector_type(8))) short bf16x8;
typedef __attribute__((ext_vector_type(4))) float f32x4;

static __device__ __forceinline__ unsigned short f2bf(float f) {
  union { float f; unsigned u; } v; v.f = f;
  unsigned r = v.u + 0x7FFFu + ((v.u >> 16) & 1u);
  return (unsigned short)(r >> 16);
}
static __device__ __forceinline__ float bf2f(unsigned short h) {
  union { unsigned u; float f; } v; v.u = ((unsigned)h) << 16;
  return v.f;
}

// blocks [0,196): coarse LDS histogram of dst>>8 (NO global per-node atomics).
// blocks [196,228): Wt[n][k] bf16 combined (k<128: W_gcn, k>=128: W_lin).
// blocks [228,1791): x -> bf16 xb (unscaled).
__global__ __launch_bounds__(256) void k_p0(
    const int* __restrict__ dst, int* __restrict__ coarseCnt,
    const float* __restrict__ Wg, const float* __restrict__ Wl,
    unsigned short* __restrict__ Wt, const float4* __restrict__ x4,
    ushort4* __restrict__ xb4) {
  int b = blockIdx.x, t = threadIdx.x;
  if (b < NEB) {
    __shared__ int cnt[CB];
    for (int i = t; i < CB; i += 256) cnt[i] = 0;
    __syncthreads();
    int e0 = b * EBLK;
    for (int i = t; i < EBLK; i += 256) {
      int e = e0 + i;
      if (e < EE) atomicAdd(&cnt[dst[e] >> 8], 1);
    }
    __syncthreads();
    for (int i = t; i < CB; i += 256)
      if (cnt[i]) atomicAdd(&coarseCnt[i], cnt[i]);
  } else if (b < NEB + 32) {
    for (int i = (b - NEB) * 256 + t; i < DD * 256; i += 32 * 256) {
      int n = i >> 8, k = i & 255;
      float v = (k < 128) ? Wg[k * DD + n] : Wl[(k - 128) * DD + n];
      Wt[i] = f2bf(v);
    }
  } else {
    int base = (b - NEB - 32) * 1024 + t;
#pragma unroll
    for (int k = 0; k < 4; k++) {
      int i = base + k * 256;
      if (i < NN * 32) {
        float4 v = x4[i];
        ushort4 o;
        o.x = f2bf(v.x); o.y = f2bf(v.y); o.z = f2bf(v.z); o.w = f2bf(v.w);
        xb4[i] = o;
      }
    }
  }
}

// Bin edges into coarse-bucket runs. Self-computes bucket bases from
// coarseCnt (LDS scan) -- no separate pscan dispatch.
// Record: src(16b) | dlocal(8b)<<16 | coarse(8b)<<24.
__global__ __launch_bounds__(512) void k_p1a(const int* __restrict__ src,
                                             const int* __restrict__ dst,
                                             const int* __restrict__ coarseCnt,
                                             int* __restrict__ cursor0,
                                             unsigned int* __restrict__ pairs) {
  __shared__ unsigned int stage[EBLK];   // 16 KB
  __shared__ int sc[256];
  __shared__ int cnt[CB], rb[CB], cur[CB];
  int t = threadIdx.x;
  int e0 = blockIdx.x * EBLK;
  int own = 0;
  if (t < CB) { cnt[t] = 0; cur[t] = 0; }
  if (t < 256) { own = (t < CB) ? coarseCnt[t] : 0; sc[t] = own; }
  __syncthreads();
  for (int i = t; i < EBLK; i += 512) {
    int e = e0 + i;
    unsigned int p = 0xFFFFFFFFu;
    if (e < EE) {
      int d = dst[e], s = src[e];
      int cb = d >> 8;
      p = (unsigned int)s | ((unsigned int)(d & 255) << 16) | ((unsigned int)cb << 24);
      atomicAdd(&cnt[cb], 1);
    }
    stage[i] = p;
  }
  // inclusive scan of sc[0..255] (global bucket bases)
  for (int off = 1; off < 256; off <<= 1) {
    __syncthreads();
    int tmp = (t < 256 && t >= off) ? sc[t - off] : 0;
    __syncthreads();
    if (t < 256 && t >= off) sc[t] += tmp;
  }
  __syncthreads();   // also guarantees count loop + cnt[] complete
  if (t < CB) {
    int excl = sc[t] - own;
    rb[t] = excl + (cnt[t] ? atomicAdd(&cursor0[t], cnt[t]) : 0);
  }
  __syncthreads();
  for (int i = t; i < EBLK; i += 512) {
    unsigned int p = stage[i];
    if (p != 0xFFFFFFFFu) {
      int cb = p >> 24;
      int ofs = atomicAdd(&cur[cb], 1);
      pairs[rb[cb] + ofs] = p;
    }
  }
}

// One block per coarse bucket: self-computed start, LDS histogram from pairs
// (deg), scan -> rowStart/dinv, scatter -> u16 srcList, xs = dinv*xb rows.
__global__ __launch_bounds__(512) void k_p1b(
    const unsigned int* __restrict__ pairs, const int* __restrict__ coarseCnt,
    const unsigned short* __restrict__ xb,
    int* __restrict__ deg, float* __restrict__ dinv, int* __restrict__ rowStart,
    unsigned short* __restrict__ srcU16, unsigned short* __restrict__ xs) {
  __shared__ int ldeg[256], lscan[256], lcur[256];
  __shared__ float ldinvs[256];
  __shared__ int wsum[8];
  int b = blockIdx.x, t = threadIdx.x;
  int n0 = b << 8;
  int nloc = NN - n0; if (nloc > 256) nloc = 256;
  // start = sum(coarseCnt[0..b-1]) via strided partials + wave reduce
  int partial = 0;
  for (int i = t; i < b; i += 512) partial += coarseCnt[i];
#pragma unroll
  for (int off = 32; off > 0; off >>= 1) partial += __shfl_xor(partial, off);
  if ((t & 63) == 0) wsum[t >> 6] = partial;
  if (t < 256) ldeg[t] = 0;
  __syncthreads();
  int start = wsum[0] + wsum[1] + wsum[2] + wsum[3] +
              wsum[4] + wsum[5] + wsum[6] + wsum[7];
  int cnt = coarseCnt[b];
  for (int i = t; i < cnt; i += 512)
    atomicAdd(&ldeg[(pairs[start + i] >> 16) & 255], 1);
  __syncthreads();
  int dg = (t < 256) ? ldeg[t] : 0;
  if (t < 256) lscan[t] = dg;
  for (int off = 1; off < 256; off <<= 1) {
    __syncthreads();
    int tmp = (t < 256 && t >= off) ? lscan[t - off] : 0;
    __syncthreads();
    if (t < 256 && t >= off) lscan[t] += tmp;
  }
  __syncthreads();
  if (t < 256) {
    int rs = start + lscan[t] - dg;
    lcur[t] = rs;
    float di = rsqrtf((float)(dg + 1));
    ldinvs[t] = di;
    if (t < nloc) { deg[n0 + t] = dg; dinv[n0 + t] = di; rowStart[n0 + t] = rs; }
  }
  __syncthreads();
  for (int i = t; i < cnt; i += 512) {
    unsigned int pr = pairs[start + i];
    int pos = atomicAdd(&lcur[(pr >> 16) & 255], 1);
    srcU16[pos] = (unsigned short)(pr & 0xFFFFu);
  }
  // xs rows (pre-scaled by dinv)
  for (int i = t; i < nloc * 16; i += 512) {
    int rr = i >> 4, q = i & 15;
    bf16x8 v = *(const bf16x8*)(xb + (size_t)(n0 + rr) * DD + q * 8);
    float di = ldinvs[rr];
    bf16x8 o;
#pragma unroll
    for (int k = 0; k < 8; k++) o[k] = (short)f2bf(bf2f((unsigned short)v[k]) * di);
    *(bf16x8*)(xs + (size_t)(n0 + rr) * DD + q * 8) = o;
  }
}

// Gather a node's CSR range into acc[8] (lane slice r*8), 8 rows in flight.
static __device__ __forceinline__ void gather16(
    const unsigned short* __restrict__ xs, const unsigned short* __restrict__ srcU16,
    int js, int cnt, int r, int srcLaneBase, float* acc) {
  for (int base = 0; base < cnt; base += 16) {
    int idx = (base + r < cnt) ? (int)srcU16[js + base + r] : 0;
    int m = cnt - base; if (m > 16) m = 16;
    int j = 0;
    for (; j + 8 <= m; j += 8) {
      int s0 = __shfl(idx, srcLaneBase + j);
      int s1 = __shfl(idx, srcLaneBase + j + 1);
      int s2 = __shfl(idx, srcLaneBase + j + 2);
      int s3 = __shfl(idx, srcLaneBase + j + 3);
      int s4 = __shfl(idx, srcLaneBase + j + 4);
      int s5 = __shfl(idx, srcLaneBase + j + 5);
      int s6 = __shfl(idx, srcLaneBase + j + 6);
      int s7 = __shfl(idx, srcLaneBase + j + 7);
      bf16x8 v0 = *(const bf16x8*)(xs + (size_t)s0 * DD + r * 8);
      bf16x8 v1 = *(const bf16x8*)(xs + (size_t)s1 * DD + r * 8);
      bf16x8 v2 = *(const bf16x8*)(xs + (size_t)s2 * DD + r * 8);
      bf16x8 v3 = *(const bf16x8*)(xs + (size_t)s3 * DD + r * 8);
      bf16x8 v4 = *(const bf16x8*)(xs + (size_t)s4 * DD + r * 8);
      bf16x8 v5 = *(const bf16x8*)(xs + (size_t)s5 * DD + r * 8);
      bf16x8 v6 = *(const bf16x8*)(xs + (size_t)s6 * DD + r * 8);
      bf16x8 v7 = *(const bf16x8*)(xs + (size_t)s7 * DD + r * 8);
#pragma unroll
      for (int k = 0; k < 8; k++) acc[k] += bf2f((unsigned short)v0[k]);
#pragma unroll
      for (int k = 0; k < 8; k++) acc[k] += bf2f((unsigned short)v1[k]);
#pragma unroll
      for (int k = 0; k < 8; k++) acc[k] += bf2f((unsigned short)v2[k]);
#pragma unroll
      for (int k = 0; k < 8; k++) acc[k] += bf2f((unsigned short)v3[k]);
#pragma unroll
      for (int k = 0; k < 8; k++) acc[k] += bf2f((unsigned short)v4[k]);
#pragma unroll
      for (int k = 0; k < 8; k++) acc[k] += bf2f((unsigned short)v5[k]);
#pragma unroll
      for (int k = 0; k < 8; k++) acc[k] += bf2f((unsigned short)v6[k]);
#pragma unroll
      for (int k = 0; k < 8; k++) acc[k] += bf2f((unsigned short)v7[k]);
    }
    for (; j < m; j++) {
      int s = __shfl(idx, srcLaneBase + j);
      bf16x8 v = *(const bf16x8*)(xs + (size_t)s * DD + r * 8);
#pragma unroll
      for (int k = 0; k < 8; k++) acc[k] += bf2f((unsigned short)v[k]);
    }
  }
}

// One block per 32-node fine bucket: register gather from u16 CSR, then
// MFMA [agg|x]@[Wg;Wl] + bias + LayerNorm (fused, no agg round-trip).
__global__ __launch_bounds__(256) void k_mega3(
    const unsigned short* __restrict__ xs, const unsigned short* __restrict__ xb,
    const int* __restrict__ rowStart, const int* __restrict__ deg,
    const unsigned short* __restrict__ srcU16, const float* __restrict__ dinv,
    const unsigned short* __restrict__ Wt, const float* __restrict__ bgcn,
    const float* __restrict__ lnw, const float* __restrict__ lnb,
    float* __restrict__ out) {
  __shared__ unsigned short abuf[32 * 136];  // 8.7 KB
  int b = blockIdx.x, t = threadIdx.x;
  int n0 = b * 32;
  int g = t >> 4, r = t & 15;
  int lane = t & 63;
  int srcLaneBase = lane & 48;
  int nA = n0 + g;           // always < NN
  int nB = n0 + g + 16;
  bool vB = (nB < NN);
  float acc0[8], acc1[8];
  {  // self-loop init from pre-scaled xs
    bf16x8 va = *(const bf16x8*)(xs + (size_t)nA * DD + r * 8);
#pragma unroll
    for (int k = 0; k < 8; k++) acc0[k] = bf2f((unsigned short)va[k]);
    if (vB) {
      bf16x8 vb = *(const bf16x8*)(xs + (size_t)nB * DD + r * 8);
#pragma unroll
      for (int k = 0; k < 8; k++) acc1[k] = bf2f((unsigned short)vb[k]);
    } else {
#pragma unroll
      for (int k = 0; k < 8; k++) acc1[k] = 0.f;
    }
  }
  gather16(xs, srcU16, rowStart[nA], deg[nA], r, srcLaneBase, acc0);
  if (vB) gather16(xs, srcU16, rowStart[nB], deg[nB], r, srcLaneBase, acc1);
  {
    float dA = dinv[nA];
    bf16x8 oa, ob;
#pragma unroll
    for (int k = 0; k < 8; k++) oa[k] = (short)f2bf(acc0[k] * dA);
    if (vB) {
      float dB = dinv[nB];
#pragma unroll
      for (int k = 0; k < 8; k++) ob[k] = (short)f2bf(acc1[k] * dB);
    } else {
#pragma unroll
      for (int k = 0; k < 8; k++) ob[k] = 0;
    }
    *(bf16x8*)&abuf[g * 136 + r * 8] = oa;
    *(bf16x8*)&abuf[(g + 16) * 136 + r * 8] = ob;
  }
  __syncthreads();
  if (t < 128) {  // waves 0,1: two 16-row MFMA tiles + fused LayerNorm
    int w = t >> 6, lane2 = t & 63;
    int quad = lane2 >> 4, rr = lane2 & 15;
    int mloc = w * 16 + rr;
    int rowA = n0 + mloc; int rc = (rowA < NN) ? rowA : (NN - 1);
    f32x4 zero = {0.f, 0.f, 0.f, 0.f};
    f32x4 macc[8];
#pragma unroll
    for (int i = 0; i < 8; i++) macc[i] = zero;
#pragma unroll
    for (int ks = 0; ks < 8; ks++) {
      bf16x8 a;
      if (ks < 4) a = *(const bf16x8*)&abuf[mloc * 136 + ks * 32 + quad * 8];
      else        a = *(const bf16x8*)(xb + (size_t)rc * DD + (ks - 4) * 32 + quad * 8);
#pragma unroll
      for (int nt = 0; nt < 8; nt++) {
        bf16x8 bb = *(const bf16x8*)(Wt + (size_t)(nt * 16 + rr) * 256 + ks * 32 + quad * 8);
        macc[nt] = __builtin_amdgcn_mfma_f32_16x16x32_bf16(a, bb, macc[nt], 0, 0, 0);
      }
    }
    float bg[8], lw[8], lb[8];
#pragma unroll
    for (int nt = 0; nt < 8; nt++) {
      int col = nt * 16 + rr;
      bg[nt] = bgcn[col] + 1e-6f;
      lw[nt] = lnw[col];
      lb[nt] = lnb[col];
    }
#pragma unroll
    for (int reg = 0; reg < 4; reg++) {
      float y[8];
      float s1 = 0.f, s2 = 0.f;
#pragma unroll
      for (int nt = 0; nt < 8; nt++) {
        y[nt] = macc[nt][reg] + bg[nt];
        s1 += y[nt];
        s2 += y[nt] * y[nt];
      }
#pragma unroll
      for (int off = 1; off < 16; off <<= 1) {
        s1 += __shfl_xor(s1, off);
        s2 += __shfl_xor(s2, off);
      }
      float mu = s1 * (1.0f / 128.0f);
      float var = s2 * (1.0f / 128.0f) - mu * mu;
      float inv = rsqrtf(var + 1e-5f);
      int row = n0 + w * 16 + quad * 4 + reg;
      if (row < NN) {
#pragma unroll
        for (int nt = 0; nt < 8; nt++) {
          out[(size_t)row * DD + nt * 16 + rr] = (y[nt] - mu) * inv * lw[nt] + lb[nt];
        }
      }
    }
  }
}

extern "C" void kernel_launch(void* const* d_in, const int* in_sizes, int n_in,
                              void* d_out, int out_size, void* d_ws, size_t ws_size,
                              hipStream_t stream) {
  const int* adj = (const int*)d_in[0];
  const float* x = (const float*)d_in[1];
  const float* Wg = (const float*)d_in[2];
  const float* bg = (const float*)d_in[3];
  const float* Wl = (const float*)d_in[4];
  const float* lw = (const float*)d_in[5];
  const float* lb = (const float*)d_in[6];
  const int* srcp = adj;
  const int* dstp = adj + EE;
  float* out = (float*)d_out;

  char* ws = (char*)d_ws;
  size_t off = 0;
  auto alloc = [&](size_t bytes) -> void* {
    void* p = ws + off;
    off += (bytes + 255) & ~(size_t)255;
    return p;
  };
  // one contiguous zero region: coarseCnt | cursor0
  int* zb = (int*)alloc((size_t)512 * 4);
  int* coarseCnt = zb;
  int* cursor0 = zb + 256;
  unsigned int* pairs = (unsigned int*)alloc((size_t)EE * 4);
  unsigned short* srcU16 = (unsigned short*)alloc((size_t)EE * 2);
  int* deg = (int*)alloc((size_t)NN * 4);
  float* dinv = (float*)alloc((size_t)NN * 4);
  int* rowStart = (int*)alloc((size_t)NN * 4);
  unsigned short* xb = (unsigned short*)alloc((size_t)NN * DD * 2);
  unsigned short* xs = (unsigned short*)alloc((size_t)NN * DD * 2);
  unsigned short* Wt = (unsigned short*)alloc((size_t)DD * 256 * 2);
  (void)ws_size; (void)in_sizes; (void)n_in; (void)out_size;

  hipMemsetAsync(zb, 0, (size_t)512 * 4, stream);
  k_p0<<<NEB + 32 + 1563, 256, 0, stream>>>(dstp, coarseCnt, Wg, Wl, Wt,
                                            (const float4*)x, (ushort4*)xb);
  k_p1a<<<NEB, 512, 0, stream>>>(srcp, dstp, coarseCnt, cursor0, pairs);
  k_p1b<<<CB, 512, 0, stream>>>(pairs, coarseCnt, xb, deg, dinv, rowStart,
                                srcU16, xs);
  k_mega3<<<NFB, 256, 0, stream>>>(xs, xb, rowStart, deg, srcU16, dinv, Wt,
                                   bg, lw, lb, out);
}

// Round 10
// 184.585 us; speedup vs baseline: 1.1801x; 1.0297x over previous
//
#include <hip/hip_runtime.h>
#include <hip/hip_bf16.h>

#define NN 50000
#define EE 800000
#define DD 128
#define CB 196      // coarse buckets of 256 nodes (196*256 = 50176)
#define NFB 1563    // fine buckets of 32 nodes (mega grid)
#define EBLK 4096
#define NEB 196     // ceil(EE/EBLK)

typedef __attribute__((ext_vector_type(8))) short bf16x8;
typedef __attribute__((ext_vector_type(4))) float f32x4;

static __device__ __forceinline__ unsigned short f2bf(float f) {
  union { float f; unsigned u; } v; v.f = f;
  unsigned r = v.u + 0x7FFFu + ((v.u >> 16) & 1u);
  return (unsigned short)(r >> 16);
}
static __device__ __forceinline__ float bf2f(unsigned short h) {
  union { unsigned u; float f; } v; v.u = ((unsigned)h) << 16;
  return v.f;
}

// blocks [0,196): coarse LDS histogram of dst>>8.
// blocks [196,228): Wt[n][k] bf16 combined (k<128: W_gcn, k>=128: W_lin).
// blocks [228,1791): x -> bf16 xb (unscaled).
__global__ __launch_bounds__(256) void k_p0(
    const int* __restrict__ dst, int* __restrict__ coarseCnt,
    const float* __restrict__ Wg, const float* __restrict__ Wl,
    unsigned short* __restrict__ Wt, const float4* __restrict__ x4,
    ushort4* __restrict__ xb4) {
  int b = blockIdx.x, t = threadIdx.x;
  if (b < NEB) {
    __shared__ int cnt[CB];
    for (int i = t; i < CB; i += 256) cnt[i] = 0;
    __syncthreads();
    int e0 = b * EBLK;
    for (int i = t; i < EBLK; i += 256) {
      int e = e0 + i;
      if (e < EE) atomicAdd(&cnt[dst[e] >> 8], 1);
    }
    __syncthreads();
    for (int i = t; i < CB; i += 256)
      if (cnt[i]) atomicAdd(&coarseCnt[i], cnt[i]);
  } else if (b < NEB + 32) {
    for (int i = (b - NEB) * 256 + t; i < DD * 256; i += 32 * 256) {
      int n = i >> 8, k = i & 255;
      float v = (k < 128) ? Wg[k * DD + n] : Wl[(k - 128) * DD + n];
      Wt[i] = f2bf(v);
    }
  } else {
    int base = (b - NEB - 32) * 1024 + t;
#pragma unroll
    for (int k = 0; k < 4; k++) {
      int i = base + k * 256;
      if (i < NN * 32) {
        float4 v = x4[i];
        ushort4 o;
        o.x = f2bf(v.x); o.y = f2bf(v.y); o.z = f2bf(v.z); o.w = f2bf(v.w);
        xb4[i] = o;
      }
    }
  }
}

// Bin edges into coarse-bucket runs. Self-computes bucket bases from
// coarseCnt (LDS scan). Record: src(16b) | dlocal(8b)<<16 | coarse(8b)<<24.
__global__ __launch_bounds__(512) void k_p1a(const int* __restrict__ src,
                                             const int* __restrict__ dst,
                                             const int* __restrict__ coarseCnt,
                                             int* __restrict__ cursor0,
                                             unsigned int* __restrict__ pairs) {
  __shared__ unsigned int stage[EBLK];   // 16 KB
  __shared__ int sc[256];
  __shared__ int cnt[CB], rb[CB], cur[CB];
  int t = threadIdx.x;
  int e0 = blockIdx.x * EBLK;
  int own = 0;
  if (t < CB) { cnt[t] = 0; cur[t] = 0; }
  if (t < 256) { own = (t < CB) ? coarseCnt[t] : 0; sc[t] = own; }
  __syncthreads();
  for (int i = t; i < EBLK; i += 512) {
    int e = e0 + i;
    unsigned int p = 0xFFFFFFFFu;
    if (e < EE) {
      int d = dst[e], s = src[e];
      int cb = d >> 8;
      p = (unsigned int)s | ((unsigned int)(d & 255) << 16) | ((unsigned int)cb << 24);
      atomicAdd(&cnt[cb], 1);
    }
    stage[i] = p;
  }
  for (int off = 1; off < 256; off <<= 1) {
    __syncthreads();
    int tmp = (t < 256 && t >= off) ? sc[t - off] : 0;
    __syncthreads();
    if (t < 256 && t >= off) sc[t] += tmp;
  }
  __syncthreads();
  if (t < CB) {
    int excl = sc[t] - own;
    rb[t] = excl + (cnt[t] ? atomicAdd(&cursor0[t], cnt[t]) : 0);
  }
  __syncthreads();
  for (int i = t; i < EBLK; i += 512) {
    unsigned int p = stage[i];
    if (p != 0xFFFFFFFFu) {
      int cb = p >> 24;
      int ofs = atomicAdd(&cur[cb], 1);
      pairs[rb[cb] + ofs] = p;
    }
  }
}

// One block per coarse bucket: self-computed start, LDS histogram from pairs,
// scan -> rowStart/dinv, scatter -> u16 srcList, xs = dinv*xb rows.
__global__ __launch_bounds__(512) void k_p1b(
    const unsigned int* __restrict__ pairs, const int* __restrict__ coarseCnt,
    const unsigned short* __restrict__ xb,
    int* __restrict__ deg, float* __restrict__ dinv, int* __restrict__ rowStart,
    unsigned short* __restrict__ srcU16, unsigned short* __restrict__ xs) {
  __shared__ int ldeg[256], lscan[256], lcur[256];
  __shared__ float ldinvs[256];
  __shared__ int wsum[8];
  int b = blockIdx.x, t = threadIdx.x;
  int n0 = b << 8;
  int nloc = NN - n0; if (nloc > 256) nloc = 256;
  int partial = 0;
  for (int i = t; i < b; i += 512) partial += coarseCnt[i];
#pragma unroll
  for (int off = 32; off > 0; off >>= 1) partial += __shfl_xor(partial, off);
  if ((t & 63) == 0) wsum[t >> 6] = partial;
  if (t < 256) ldeg[t] = 0;
  __syncthreads();
  int start = wsum[0] + wsum[1] + wsum[2] + wsum[3] +
              wsum[4] + wsum[5] + wsum[6] + wsum[7];
  int cnt = coarseCnt[b];
  for (int i = t; i < cnt; i += 512)
    atomicAdd(&ldeg[(pairs[start + i] >> 16) & 255], 1);
  __syncthreads();
  int dg = (t < 256) ? ldeg[t] : 0;
  if (t < 256) lscan[t] = dg;
  for (int off = 1; off < 256; off <<= 1) {
    __syncthreads();
    int tmp = (t < 256 && t >= off) ? lscan[t - off] : 0;
    __syncthreads();
    if (t < 256 && t >= off) lscan[t] += tmp;
  }
  __syncthreads();
  if (t < 256) {
    int rs = start + lscan[t] - dg;
    lcur[t] = rs;
    float di = rsqrtf((float)(dg + 1));
    ldinvs[t] = di;
    if (t < nloc) { deg[n0 + t] = dg; dinv[n0 + t] = di; rowStart[n0 + t] = rs; }
  }
  __syncthreads();
  for (int i = t; i < cnt; i += 512) {
    unsigned int pr = pairs[start + i];
    int pos = atomicAdd(&lcur[(pr >> 16) & 255], 1);
    srcU16[pos] = (unsigned short)(pr & 0xFFFFu);
  }
  for (int i = t; i < nloc * 16; i += 512) {
    int rr = i >> 4, q = i & 15;
    bf16x8 v = *(const bf16x8*)(xb + (size_t)(n0 + rr) * DD + q * 8);
    float di = ldinvs[rr];
    bf16x8 o;
#pragma unroll
    for (int k = 0; k < 8; k++) o[k] = (short)f2bf(bf2f((unsigned short)v[k]) * di);
    *(bf16x8*)(xs + (size_t)(n0 + rr) * DD + q * 8) = o;
  }
}

// Gather a node's CSR range into acc[8] (lane slice r*8), 8 rows in flight.
static __device__ __forceinline__ void gather16(
    const unsigned short* __restrict__ xs, const unsigned short* __restrict__ srcU16,
    int js, int cnt, int r, int srcLaneBase, float* acc) {
  for (int base = 0; base < cnt; base += 16) {
    int idx = (base + r < cnt) ? (int)srcU16[js + base + r] : 0;
    int m = cnt - base; if (m > 16) m = 16;
    int j = 0;
    for (; j + 8 <= m; j += 8) {
      int s0 = __shfl(idx, srcLaneBase + j);
      int s1 = __shfl(idx, srcLaneBase + j + 1);
      int s2 = __shfl(idx, srcLaneBase + j + 2);
      int s3 = __shfl(idx, srcLaneBase + j + 3);
      int s4 = __shfl(idx, srcLaneBase + j + 4);
      int s5 = __shfl(idx, srcLaneBase + j + 5);
      int s6 = __shfl(idx, srcLaneBase + j + 6);
      int s7 = __shfl(idx, srcLaneBase + j + 7);
      bf16x8 v0 = *(const bf16x8*)(xs + (size_t)s0 * DD + r * 8);
      bf16x8 v1 = *(const bf16x8*)(xs + (size_t)s1 * DD + r * 8);
      bf16x8 v2 = *(const bf16x8*)(xs + (size_t)s2 * DD + r * 8);
      bf16x8 v3 = *(const bf16x8*)(xs + (size_t)s3 * DD + r * 8);
      bf16x8 v4 = *(const bf16x8*)(xs + (size_t)s4 * DD + r * 8);
      bf16x8 v5 = *(const bf16x8*)(xs + (size_t)s5 * DD + r * 8);
      bf16x8 v6 = *(const bf16x8*)(xs + (size_t)s6 * DD + r * 8);
      bf16x8 v7 = *(const bf16x8*)(xs + (size_t)s7 * DD + r * 8);
#pragma unroll
      for (int k = 0; k < 8; k++) acc[k] += bf2f((unsigned short)v0[k]);
#pragma unroll
      for (int k = 0; k < 8; k++) acc[k] += bf2f((unsigned short)v1[k]);
#pragma unroll
      for (int k = 0; k < 8; k++) acc[k] += bf2f((unsigned short)v2[k]);
#pragma unroll
      for (int k = 0; k < 8; k++) acc[k] += bf2f((unsigned short)v3[k]);
#pragma unroll
      for (int k = 0; k < 8; k++) acc[k] += bf2f((unsigned short)v4[k]);
#pragma unroll
      for (int k = 0; k < 8; k++) acc[k] += bf2f((unsigned short)v5[k]);
#pragma unroll
      for (int k = 0; k < 8; k++) acc[k] += bf2f((unsigned short)v6[k]);
#pragma unroll
      for (int k = 0; k < 8; k++) acc[k] += bf2f((unsigned short)v7[k]);
    }
    for (; j < m; j++) {
      int s = __shfl(idx, srcLaneBase + j);
      bf16x8 v = *(const bf16x8*)(xs + (size_t)s * DD + r * 8);
#pragma unroll
      for (int k = 0; k < 8; k++) acc[k] += bf2f((unsigned short)v[k]);
    }
  }
}

// One block per 32-node bucket, 512 threads: 32 groups x 1 node gather
// (12500 waves offered -> agg2-level occupancy), then waves 0-1 run the
// MFMA [agg|x]@[Wg;Wl] + bias + LayerNorm epilogue; waves 2-7 exit.
__global__ __launch_bounds__(512) void k_mega4(
    const unsigned short* __restrict__ xs, const unsigned short* __restrict__ xb,
    const int* __restrict__ rowStart, const int* __restrict__ deg,
    const unsigned short* __restrict__ srcU16, const float* __restrict__ dinv,
    const unsigned short* __restrict__ Wt, const float* __restrict__ bgcn,
    const float* __restrict__ lnw, const float* __restrict__ lnb,
    float* __restrict__ out) {
  __shared__ unsigned short abuf[32 * 136];  // 8.7 KB
  int b = blockIdx.x, t = threadIdx.x;
  int n0 = b * 32;
  int g = t >> 4, r = t & 15;
  int lane = t & 63;
  int srcLaneBase = lane & 48;
  int node = n0 + g;
  bool valid = (node < NN);
  int nc = valid ? node : (NN - 1);
  float acc[8];
  {  // self-loop init from pre-scaled xs
    bf16x8 va = *(const bf16x8*)(xs + (size_t)nc * DD + r * 8);
#pragma unroll
    for (int k = 0; k < 8; k++) acc[k] = bf2f((unsigned short)va[k]);
  }
  int js = valid ? rowStart[nc] : 0;
  int cnt = valid ? deg[nc] : 0;
  gather16(xs, srcU16, js, cnt, r, srcLaneBase, acc);
  {
    float d = dinv[nc];
    bf16x8 o;
#pragma unroll
    for (int k = 0; k < 8; k++) o[k] = valid ? (short)f2bf(acc[k] * d) : (short)0;
    *(bf16x8*)&abuf[g * 136 + r * 8] = o;
  }
  __syncthreads();
  if (t < 128) {  // waves 0,1: two 16-row MFMA tiles + fused LayerNorm
    int w = t >> 6, lane2 = t & 63;
    int quad = lane2 >> 4, rr = lane2 & 15;
    int mloc = w * 16 + rr;
    int rowA = n0 + mloc; int rc = (rowA < NN) ? rowA : (NN - 1);
    f32x4 zero = {0.f, 0.f, 0.f, 0.f};
    f32x4 macc[8];
#pragma unroll
    for (int i = 0; i < 8; i++) macc[i] = zero;
#pragma unroll
    for (int ks = 0; ks < 8; ks++) {
      bf16x8 a;
      if (ks < 4) a = *(const bf16x8*)&abuf[mloc * 136 + ks * 32 + quad * 8];
      else        a = *(const bf16x8*)(xb + (size_t)rc * DD + (ks - 4) * 32 + quad * 8);
#pragma unroll
      for (int nt = 0; nt < 8; nt++) {
        bf16x8 bb = *(const bf16x8*)(Wt + (size_t)(nt * 16 + rr) * 256 + ks * 32 + quad * 8);
        macc[nt] = __builtin_amdgcn_mfma_f32_16x16x32_bf16(a, bb, macc[nt], 0, 0, 0);
      }
    }
    float bg[8], lw[8], lb[8];
#pragma unroll
    for (int nt = 0; nt < 8; nt++) {
      int col = nt * 16 + rr;
      bg[nt] = bgcn[col] + 1e-6f;
      lw[nt] = lnw[col];
      lb[nt] = lnb[col];
    }
#pragma unroll
    for (int reg = 0; reg < 4; reg++) {
      float y[8];
      float s1 = 0.f, s2 = 0.f;
#pragma unroll
      for (int nt = 0; nt < 8; nt++) {
        y[nt] = macc[nt][reg] + bg[nt];
        s1 += y[nt];
        s2 += y[nt] * y[nt];
      }
#pragma unroll
      for (int off = 1; off < 16; off <<= 1) {
        s1 += __shfl_xor(s1, off);
        s2 += __shfl_xor(s2, off);
      }
      float mu = s1 * (1.0f / 128.0f);
      float var = s2 * (1.0f / 128.0f) - mu * mu;
      float inv = rsqrtf(var + 1e-5f);
      int row = n0 + w * 16 + quad * 4 + reg;
      if (row < NN) {
#pragma unroll
        for (int nt = 0; nt < 8; nt++) {
          out[(size_t)row * DD + nt * 16 + rr] = (y[nt] - mu) * inv * lw[nt] + lb[nt];
        }
      }
    }
  }
}

extern "C" void kernel_launch(void* const* d_in, const int* in_sizes, int n_in,
                              void* d_out, int out_size, void* d_ws, size_t ws_size,
                              hipStream_t stream) {
  const int* adj = (const int*)d_in[0];
  const float* x = (const float*)d_in[1];
  const float* Wg = (const float*)d_in[2];
  const float* bg = (const float*)d_in[3];
  const float* Wl = (const float*)d_in[4];
  const float* lw = (const float*)d_in[5];
  const float* lb = (const float*)d_in[6];
  const int* srcp = adj;
  const int* dstp = adj + EE;
  float* out = (float*)d_out;

  char* ws = (char*)d_ws;
  size_t off = 0;
  auto alloc = [&](size_t bytes) -> void* {
    void* p = ws + off;
    off += (bytes + 255) & ~(size_t)255;
    return p;
  };
  int* zb = (int*)alloc((size_t)512 * 4);
  int* coarseCnt = zb;
  int* cursor0 = zb + 256;
  unsigned int* pairs = (unsigned int*)alloc((size_t)EE * 4);
  unsigned short* srcU16 = (unsigned short*)alloc((size_t)EE * 2);
  int* deg = (int*)alloc((size_t)NN * 4);
  float* dinv = (float*)alloc((size_t)NN * 4);
  int* rowStart = (int*)alloc((size_t)NN * 4);
  unsigned short* xb = (unsigned short*)alloc((size_t)NN * DD * 2);
  unsigned short* xs = (unsigned short*)alloc((size_t)NN * DD * 2);
  unsigned short* Wt = (unsigned short*)alloc((size_t)DD * 256 * 2);
  (void)ws_size; (void)in_sizes; (void)n_in; (void)out_size;

  hipMemsetAsync(zb, 0, (size_t)512 * 4, stream);
  k_p0<<<NEB + 32 + 1563, 256, 0, stream>>>(dstp, coarseCnt, Wg, Wl, Wt,
                                            (const float4*)x, (ushort4*)xb);
  k_p1a<<<NEB, 512, 0, stream>>>(srcp, dstp, coarseCnt, cursor0, pairs);
  k_p1b<<<CB, 512, 0, stream>>>(pairs, coarseCnt, xb, deg, dinv, rowStart,
                                srcU16, xs);
  k_mega4<<<NFB, 512, 0, stream>>>(xs, xb, rowStart, deg, srcU16, dinv, Wt,
                                   bg, lw, lb, out);
}